// Round 8
// baseline (135.409 us; speedup 1.0000x reference)
//
#include <hip/hip_runtime.h>

typedef __bf16 bf16_t;
typedef bf16_t bf16x8 __attribute__((ext_vector_type(8)));
typedef bf16_t bf16x4 __attribute__((ext_vector_type(4)));
typedef float f32x4 __attribute__((ext_vector_type(4)));

// load 8 contiguous elements as bf16x8 (fp32 source converts in-register)
__device__ inline bf16x8 ld8(const float* p) {
    f32x4 a = *reinterpret_cast<const f32x4*>(p);
    f32x4 b = *reinterpret_cast<const f32x4*>(p + 4);
    bf16x8 r = { (bf16_t)a[0], (bf16_t)a[1], (bf16_t)a[2], (bf16_t)a[3],
                 (bf16_t)b[0], (bf16_t)b[1], (bf16_t)b[2], (bf16_t)b[3] };
    return r;
}
__device__ inline bf16x8 ld8(const bf16_t* p) {
    return *reinterpret_cast<const bf16x8*>(p);
}

// ---------------- GEMM: C = A * B^T (+bias); fp32/bf16 sources converted during staging ----------------
// 64x64 tile, BK=64, software-pipelined, XCD-aware 1-D grid remap.
template <typename AT, typename BT, typename OUT_T, bool HAS_BIAS>
__global__ __launch_bounds__(256) void gemm_bt(
    const AT* __restrict__ A, const BT* __restrict__ B,
    OUT_T* __restrict__ C, const float* __restrict__ bias,
    int K, int lda, int ldb, int ldc)
{
    const int l  = blockIdx.x;
    const int lp = (l & 7) * (gridDim.x >> 3) + (l >> 3);   // bijective XCD chunking (total%8==0)
    const int m0 = (lp & 7) * 64;                           // 8 m-tiles (M=512)
    const int n0 = (lp >> 3) * 64;

    __shared__ __align__(16) bf16_t As[64][72];   // +8 pad -> 2-way bank alias (free)
    __shared__ __align__(16) bf16_t Bs[64][72];

    const int tid  = threadIdx.x;
    const int lane = tid & 63;
    const int wave = tid >> 6;
    const int srow = tid >> 3;          // 0..31 (second chunk: +32)
    const int soff = (tid & 7) * 8;     // 0,8,..,56

    bf16x8 rA0, rA1, rB0, rB1;
    rA0 = ld8(&A[(long)(m0 + srow)      * lda + soff]);
    rA1 = ld8(&A[(long)(m0 + srow + 32) * lda + soff]);
    rB0 = ld8(&B[(long)(n0 + srow)      * ldb + soff]);
    rB1 = ld8(&B[(long)(n0 + srow + 32) * ldb + soff]);

    f32x4 acc[4] = {};

    for (int k0 = 0; k0 < K; k0 += 64) {
        *reinterpret_cast<bf16x8*>(&As[srow][soff])      = rA0;
        *reinterpret_cast<bf16x8*>(&As[srow + 32][soff]) = rA1;
        *reinterpret_cast<bf16x8*>(&Bs[srow][soff])      = rB0;
        *reinterpret_cast<bf16x8*>(&Bs[srow + 32][soff]) = rB1;
        __syncthreads();

        if (k0 + 64 < K) {              // issue next-tile loads; consumed after next barrier
            rA0 = ld8(&A[(long)(m0 + srow)      * lda + k0 + 64 + soff]);
            rA1 = ld8(&A[(long)(m0 + srow + 32) * lda + k0 + 64 + soff]);
            rB0 = ld8(&B[(long)(n0 + srow)      * ldb + k0 + 64 + soff]);
            rB1 = ld8(&B[(long)(n0 + srow + 32) * ldb + k0 + 64 + soff]);
        }

#pragma unroll
        for (int ks = 0; ks < 64; ks += 32) {
            bf16x8 af = *reinterpret_cast<const bf16x8*>(&As[wave * 16 + (lane & 15)][(lane >> 4) * 8 + ks]);
#pragma unroll
            for (int nf = 0; nf < 4; ++nf) {
                bf16x8 bfr = *reinterpret_cast<const bf16x8*>(&Bs[nf * 16 + (lane & 15)][(lane >> 4) * 8 + ks]);
                acc[nf] = __builtin_amdgcn_mfma_f32_16x16x32_bf16(af, bfr, acc[nf], 0, 0, 0);
            }
        }
        __syncthreads();
    }

    const int crow0 = m0 + wave * 16 + (lane >> 4) * 4;
    const int ccol0 = n0 + (lane & 15);
#pragma unroll
    for (int nf = 0; nf < 4; ++nf) {
        const int col = ccol0 + nf * 16;
        const float bv = HAS_BIAS ? bias[col] : 0.0f;
#pragma unroll
        for (int v = 0; v < 4; ++v) {
            C[(long)(crow0 + v) * ldc + col] = (OUT_T)(acc[nf][v] + bv);
        }
    }
}

// ---------------- fused scores + softmax + attn@(v+d): one block per (b,i,head-group) ----------------
// Block (bi, cc): computes attn rows for heads cc*4..cc*4+3 at query i in-block (q.k^T dot from
// L2-resident qkv), per-wave softmax, then streams d for the 256-col chunk (roofline part).
__global__ __launch_bounds__(256) void attnd_fused(
    const bf16_t* __restrict__ qkv,   // [B,256,2304]
    const float* __restrict__ d,      // [B,256,256,768]
    bf16_t* __restrict__ oh)          // [B,256,768]
{
    const int bi = blockIdx.x;          // b*256 + i
    const int b  = bi >> 8;
    const int i  = bi & 255;
    const int cc = blockIdx.y;          // 0..2
    const int t  = threadIdx.x;
    const int lane = t & 63, wave = t >> 6;

    __shared__ float qf[4][64];         // 4 q rows (scaled by 1/8)
    __shared__ float attn_s[4][257];    // scores -> probs
    __shared__ f32x4 partial[3][64];

    // stage q for the 4 heads of this group (256 bf16, one per thread)
    qf[t >> 6][t & 63] = (float)qkv[(long)b * 589824 + (long)i * 2304 + cc * 256 + t] * 0.125f;
    __syncthreads();

    // scores: thread t owns column j = t, all 4 heads (k gathered from L2)
    {
        const bf16_t* kp = qkv + (long)b * 589824 + 768 + (long)t * 2304 + cc * 256;
        float s[4];
#pragma unroll
        for (int hh = 0; hh < 4; ++hh) {
            float a = 0.0f;
#pragma unroll
            for (int e8 = 0; e8 < 8; ++e8) {
                bf16x8 kv = *reinterpret_cast<const bf16x8*>(kp + hh * 64 + e8 * 8);
#pragma unroll
                for (int u = 0; u < 8; ++u)
                    a = fmaf(qf[hh][e8 * 8 + u], (float)kv[u], a);
            }
            s[hh] = a;
        }
#pragma unroll
        for (int hh = 0; hh < 4; ++hh) attn_s[hh][t] = s[hh];
    }
    __syncthreads();

    // softmax: wave w = head w; lane l covers j = l, l+64, l+128, l+192
    {
        float v0 = attn_s[wave][lane],       v1 = attn_s[wave][lane + 64],
              v2 = attn_s[wave][lane + 128], v3 = attn_s[wave][lane + 192];
        float m = fmaxf(fmaxf(v0, v1), fmaxf(v2, v3));
#pragma unroll
        for (int o = 32; o > 0; o >>= 1) m = fmaxf(m, __shfl_xor(m, o));
        v0 = __expf(v0 - m); v1 = __expf(v1 - m); v2 = __expf(v2 - m); v3 = __expf(v3 - m);
        float ssum = v0 + v1 + v2 + v3;
#pragma unroll
        for (int o = 32; o > 0; o >>= 1) ssum += __shfl_xor(ssum, o);
        const float inv = 1.0f / ssum;
        attn_s[wave][lane]       = v0 * inv;
        attn_s[wave][lane + 64]  = v1 * inv;
        attn_s[wave][lane + 128] = v2 * inv;
        attn_s[wave][lane + 192] = v3 * inv;
    }
    __syncthreads();

    // stream d: wave w owns j in [w*64, w*64+64)
    const int c0 = cc * 256 + lane * 4;
    const float* arow = attn_s[lane >> 4];
    const int jb = wave * 64;
    const f32x4* dp = reinterpret_cast<const f32x4*>(d + (long)bi * 196608 + (long)jb * 768 + c0);
    const bf16_t* vp = qkv + (long)b * 589824 + (long)jb * 2304 + 1536 + c0;

    f32x4 acc = {};
#pragma unroll 8
    for (int jj = 0; jj < 64; ++jj) {
        f32x4 dv = __builtin_nontemporal_load(dp + (long)jj * 192);
        bf16x4 vv = *reinterpret_cast<const bf16x4*>(vp + (long)jj * 2304);
        float a = arow[jb + jj];
        acc[0] = fmaf(a, dv[0] + (float)vv[0], acc[0]);
        acc[1] = fmaf(a, dv[1] + (float)vv[1], acc[1]);
        acc[2] = fmaf(a, dv[2] + (float)vv[2], acc[2]);
        acc[3] = fmaf(a, dv[3] + (float)vv[3], acc[3]);
    }

    if (wave) partial[wave - 1][lane] = acc;
    __syncthreads();
    if (wave == 0) {
        acc += partial[0][lane] + partial[1][lane] + partial[2][lane];
        bf16x4 o = { (bf16_t)acc[0], (bf16_t)acc[1], (bf16_t)acc[2], (bf16_t)acc[3] };
        *reinterpret_cast<bf16x4*>(oh + (long)bi * 768 + c0) = o;
    }
}

// ---------------- launch ----------------
extern "C" void kernel_launch(void* const* d_in, const int* in_sizes, int n_in,
                              void* d_out, int out_size, void* d_ws, size_t ws_size,
                              hipStream_t stream) {
    const float* x      = (const float*)d_in[0];   // [2,256,768]
    const float* d      = (const float*)d_in[1];   // [2,256,256,768]
    const float* w_qkv  = (const float*)d_in[2];   // [2304,768]
    const float* w_proj = (const float*)d_in[3];   // [768,768]
    const float* b_proj = (const float*)d_in[4];   // [768]
    float* out = (float*)d_out;                    // [2,256,768]

    char* ws = (char*)d_ws;
    bf16_t* qkvb = (bf16_t*)(ws);                  //  512x2304 bf16
    bf16_t* oh   = (bf16_t*)(ws + 2359296);        //  512x768 bf16

    // 1. qkv = x @ w_qkv^T -> bf16 [512,2304]  (288 tiles, XCD-remapped)
    gemm_bt<float, float, bf16_t, false><<<288, 256, 0, stream>>>(
        x, w_qkv, qkvb, nullptr, 768, 768, 768, 2304);

    // 2. oh = softmax(q k^T/8) @ (v + d_pair) -> bf16 [512,768]  (scores fused in-block)
    attnd_fused<<<dim3(512, 3), 256, 0, stream>>>(qkvb, d, oh);

    // 3. out = oh @ w_proj^T + b_proj -> fp32  (96 tiles, XCD-remapped)
    gemm_bt<bf16_t, float, float, true><<<96, 256, 0, stream>>>(
        oh, w_proj, out, b_proj, 768, 768, 768, 768);
}

// Round 9
// 99.303 us; speedup vs baseline: 1.3636x; 1.3636x over previous
//
#include <hip/hip_runtime.h>

typedef __bf16 bf16_t;
typedef bf16_t bf16x8 __attribute__((ext_vector_type(8)));
typedef bf16_t bf16x4 __attribute__((ext_vector_type(4)));
typedef float f32x4 __attribute__((ext_vector_type(4)));

// load 8 contiguous elements as bf16x8 (fp32 source converts in-register)
__device__ inline bf16x8 ld8(const float* p) {
    f32x4 a = *reinterpret_cast<const f32x4*>(p);
    f32x4 b = *reinterpret_cast<const f32x4*>(p + 4);
    bf16x8 r = { (bf16_t)a[0], (bf16_t)a[1], (bf16_t)a[2], (bf16_t)a[3],
                 (bf16_t)b[0], (bf16_t)b[1], (bf16_t)b[2], (bf16_t)b[3] };
    return r;
}
__device__ inline bf16x8 ld8(const bf16_t* p) {
    return *reinterpret_cast<const bf16x8*>(p);
}

// ---------------- GEMM: C = A * B^T (+bias); fp32/bf16 sources converted during staging ----------------
// 64x64 tile, BK=64, software-pipelined, XCD-aware 1-D grid remap.
template <typename AT, typename BT, typename OUT_T, bool HAS_BIAS>
__global__ __launch_bounds__(256) void gemm_bt(
    const AT* __restrict__ A, const BT* __restrict__ B,
    OUT_T* __restrict__ C, const float* __restrict__ bias,
    int K, int lda, int ldb, int ldc)
{
    const int l  = blockIdx.x;
    const int lp = (l & 7) * (gridDim.x >> 3) + (l >> 3);   // bijective XCD chunking (total%8==0)
    const int m0 = (lp & 7) * 64;                           // 8 m-tiles (M=512)
    const int n0 = (lp >> 3) * 64;

    __shared__ __align__(16) bf16_t As[64][72];   // +8 pad -> 2-way bank alias (free)
    __shared__ __align__(16) bf16_t Bs[64][72];

    const int tid  = threadIdx.x;
    const int lane = tid & 63;
    const int wave = tid >> 6;
    const int srow = tid >> 3;          // 0..31 (second chunk: +32)
    const int soff = (tid & 7) * 8;     // 0,8,..,56

    bf16x8 rA0, rA1, rB0, rB1;
    rA0 = ld8(&A[(long)(m0 + srow)      * lda + soff]);
    rA1 = ld8(&A[(long)(m0 + srow + 32) * lda + soff]);
    rB0 = ld8(&B[(long)(n0 + srow)      * ldb + soff]);
    rB1 = ld8(&B[(long)(n0 + srow + 32) * ldb + soff]);

    f32x4 acc[4] = {};

    for (int k0 = 0; k0 < K; k0 += 64) {
        *reinterpret_cast<bf16x8*>(&As[srow][soff])      = rA0;
        *reinterpret_cast<bf16x8*>(&As[srow + 32][soff]) = rA1;
        *reinterpret_cast<bf16x8*>(&Bs[srow][soff])      = rB0;
        *reinterpret_cast<bf16x8*>(&Bs[srow + 32][soff]) = rB1;
        __syncthreads();

        if (k0 + 64 < K) {              // issue next-tile loads; consumed after next barrier
            rA0 = ld8(&A[(long)(m0 + srow)      * lda + k0 + 64 + soff]);
            rA1 = ld8(&A[(long)(m0 + srow + 32) * lda + k0 + 64 + soff]);
            rB0 = ld8(&B[(long)(n0 + srow)      * ldb + k0 + 64 + soff]);
            rB1 = ld8(&B[(long)(n0 + srow + 32) * ldb + k0 + 64 + soff]);
        }

#pragma unroll
        for (int ks = 0; ks < 64; ks += 32) {
            bf16x8 af = *reinterpret_cast<const bf16x8*>(&As[wave * 16 + (lane & 15)][(lane >> 4) * 8 + ks]);
#pragma unroll
            for (int nf = 0; nf < 4; ++nf) {
                bf16x8 bfr = *reinterpret_cast<const bf16x8*>(&Bs[nf * 16 + (lane & 15)][(lane >> 4) * 8 + ks]);
                acc[nf] = __builtin_amdgcn_mfma_f32_16x16x32_bf16(af, bfr, acc[nf], 0, 0, 0);
            }
        }
        __syncthreads();
    }

    const int crow0 = m0 + wave * 16 + (lane >> 4) * 4;
    const int ccol0 = n0 + (lane & 15);
#pragma unroll
    for (int nf = 0; nf < 4; ++nf) {
        const int col = ccol0 + nf * 16;
        const float bv = HAS_BIAS ? bias[col] : 0.0f;
#pragma unroll
        for (int v = 0; v < 4; ++v) {
            C[(long)(crow0 + v) * ldc + col] = (OUT_T)(acc[nf][v] + bv);
        }
    }
}

// ---------------- fused S = softmax((q/8) k^T) -> bf16: grid (24 bh, 4 m-tiles) ----------------
// bh fastest -> xcd = bh%8: all 4 m-tiles of one (b,h) share an XCD (K staged once per XCD).
__global__ __launch_bounds__(256) void qk_softmax(
    const bf16_t* __restrict__ qkv,   // [B,256,2304]
    bf16_t* __restrict__ probs)       // [24,256,256] bf16
{
    const int bh = blockIdx.x;
    const int b = bh / 12, h = bh % 12;
    const int m0 = blockIdx.y * 64;
    const bf16_t* qbase = qkv + (long)b * 589824 + h * 64;
    const bf16_t* kbase = qkv + (long)b * 589824 + 768 + h * 64;

    __shared__ __align__(16) bf16_t Qs[64][72];
    __shared__ __align__(16) bf16_t Ks[256][72];

    const int t = threadIdx.x;
#pragma unroll
    for (int c = 0; c < 2; ++c) {
        const int chunk = c * 256 + t;
        const int row = chunk >> 3, off = (chunk & 7) * 8;
        *reinterpret_cast<uint4*>(&Qs[row][off]) =
            *reinterpret_cast<const uint4*>(qbase + (long)(m0 + row) * 2304 + off);
    }
#pragma unroll
    for (int c = 0; c < 8; ++c) {
        const int chunk = c * 256 + t;
        const int row = chunk >> 3, off = (chunk & 7) * 8;
        *reinterpret_cast<uint4*>(&Ks[row][off]) =
            *reinterpret_cast<const uint4*>(kbase + (long)row * 2304 + off);
    }
    __syncthreads();

    const int lane = t & 63, wave = t >> 6;
    f32x4 acc[16] = {};
#pragma unroll
    for (int ks = 0; ks < 64; ks += 32) {
        bf16x8 af = *reinterpret_cast<const bf16x8*>(&Qs[wave * 16 + (lane & 15)][(lane >> 4) * 8 + ks]);
#pragma unroll
        for (int nf = 0; nf < 16; ++nf) {
            bf16x8 bfr = *reinterpret_cast<const bf16x8*>(&Ks[nf * 16 + (lane & 15)][(lane >> 4) * 8 + ks]);
            acc[nf] = __builtin_amdgcn_mfma_f32_16x16x32_bf16(af, bfr, acc[nf], 0, 0, 0);
        }
    }

    float inv[4];
#pragma unroll
    for (int v = 0; v < 4; ++v) {
        float mm = -1e30f;
#pragma unroll
        for (int nf = 0; nf < 16; ++nf) { acc[nf][v] *= 0.125f; mm = fmaxf(mm, acc[nf][v]); }
#pragma unroll
        for (int o = 1; o < 16; o <<= 1) mm = fmaxf(mm, __shfl_xor(mm, o));
        float s = 0.0f;
#pragma unroll
        for (int nf = 0; nf < 16; ++nf) { float e = __expf(acc[nf][v] - mm); acc[nf][v] = e; s += e; }
#pragma unroll
        for (int o = 1; o < 16; o <<= 1) s += __shfl_xor(s, o);
        inv[v] = 1.0f / s;
    }

    bf16_t* prow = probs + ((long)bh * 256 + m0 + wave * 16 + (lane >> 4) * 4) * 256 + (lane & 15);
#pragma unroll
    for (int nf = 0; nf < 16; ++nf) {
#pragma unroll
        for (int v = 0; v < 4; ++v) {
            prow[(long)v * 256 + nf * 16] = (bf16_t)(acc[nf][v] * inv[v]);
        }
    }
}

// ---------------- fused: oh[b,i,c] = sum_j attn * (v + d)  (roofline-verified: ~62.5us) ----------------
__global__ __launch_bounds__(256) void attnd_kernel(
    const bf16_t* __restrict__ attn,  // [24,256,256] bf16 probs
    const bf16_t* __restrict__ qkv,   // [B,256,2304]
    const float* __restrict__ d,      // [B,256,256,768]
    bf16_t* __restrict__ oh)          // [B,256,768]
{
    const int bi = blockIdx.x;
    const int b  = bi >> 8;
    const int i  = bi & 255;
    const int cc = blockIdx.y;
    const int t  = threadIdx.x;
    const int lane = t & 63, wave = t >> 6;

    __shared__ float attn_s[4 * 257];
    __shared__ f32x4 partial[3][64];

#pragma unroll
    for (int q = 0; q < 4; ++q) {
        attn_s[q * 257 + t] = (float)attn[(((long)(b * 12 + cc * 4 + q)) * 256 + i) * 256 + t];
    }
    __syncthreads();

    const int c0 = cc * 256 + lane * 4;
    const float* arow = attn_s + (lane >> 4) * 257;
    const int jb = wave * 64;
    const f32x4* dp = reinterpret_cast<const f32x4*>(d + (long)bi * 196608 + (long)jb * 768 + c0);
    const bf16_t* vp = qkv + (long)b * 589824 + (long)jb * 2304 + 1536 + c0;

    f32x4 acc = {};
#pragma unroll 8
    for (int jj = 0; jj < 64; ++jj) {
        f32x4 dv = __builtin_nontemporal_load(dp + (long)jj * 192);
        bf16x4 vv = *reinterpret_cast<const bf16x4*>(vp + (long)jj * 2304);
        float a = arow[jb + jj];
        acc[0] = fmaf(a, dv[0] + (float)vv[0], acc[0]);
        acc[1] = fmaf(a, dv[1] + (float)vv[1], acc[1]);
        acc[2] = fmaf(a, dv[2] + (float)vv[2], acc[2]);
        acc[3] = fmaf(a, dv[3] + (float)vv[3], acc[3]);
    }

    if (wave) partial[wave - 1][lane] = acc;
    __syncthreads();
    if (wave == 0) {
        acc += partial[0][lane] + partial[1][lane] + partial[2][lane];
        bf16x4 o = { (bf16_t)acc[0], (bf16_t)acc[1], (bf16_t)acc[2], (bf16_t)acc[3] };
        *reinterpret_cast<bf16x4*>(oh + (long)bi * 768 + c0) = o;
    }
}

// ---------------- launch ----------------
extern "C" void kernel_launch(void* const* d_in, const int* in_sizes, int n_in,
                              void* d_out, int out_size, void* d_ws, size_t ws_size,
                              hipStream_t stream) {
    const float* x      = (const float*)d_in[0];   // [2,256,768]
    const float* d      = (const float*)d_in[1];   // [2,256,256,768]
    const float* w_qkv  = (const float*)d_in[2];   // [2304,768]
    const float* w_proj = (const float*)d_in[3];   // [768,768]
    const float* b_proj = (const float*)d_in[4];   // [768]
    float* out = (float*)d_out;                    // [2,256,768]

    char* ws = (char*)d_ws;
    bf16_t* qkvb  = (bf16_t*)(ws);                 //  512x2304 bf16
    bf16_t* probs = (bf16_t*)(ws + 2359296);       //  24x256x256 bf16
    bf16_t* oh    = (bf16_t*)(ws + 5505024);       //  512x768 bf16

    // 1. qkv = x @ w_qkv^T -> bf16 [512,2304]  (288 tiles, XCD-remapped)
    gemm_bt<float, float, bf16_t, false><<<288, 256, 0, stream>>>(
        x, w_qkv, qkvb, nullptr, 768, 768, 768, 2304);

    // 2. probs = softmax((q/8) k^T) -> bf16 [24,256,256]
    qk_softmax<<<dim3(24, 4), 256, 0, stream>>>(qkvb, probs);

    // 3. oh = attn @ (v + d_pair) -> bf16 [512,768]
    attnd_kernel<<<dim3(512, 3), 256, 0, stream>>>(probs, qkvb, d, oh);

    // 4. out = oh @ w_proj^T + b_proj -> fp32  (96 tiles, XCD-remapped)
    gemm_bt<bf16_t, float, float, true><<<96, 256, 0, stream>>>(
        oh, w_proj, out, b_proj, 768, 768, 768, 768);
}